// Round 10
// baseline (743.625 us; speedup 1.0000x reference)
//
#include <hip/hip_runtime.h>

typedef int   i32x4 __attribute__((ext_vector_type(4)));
typedef int   i32x8 __attribute__((ext_vector_type(8)));
typedef float f32x16 __attribute__((ext_vector_type(16)));

#define D_DIM 256
#define LOG2E 1.4426950408889634f
#define LN2   0.6931471805599453f
// Transposed workspace layout: [strip of 128 rows][kc16 0..15][row 0..127][16B]
#define STRIP_BYTES 32768
#define GRID2 4096          // siglip grid: each block chains 4 row-adjacent tiles

#if __has_builtin(__builtin_amdgcn_exp2f)
static __device__ __forceinline__ float exp2_fast(float x) { return __builtin_amdgcn_exp2f(x); }
#else
static __device__ __forceinline__ float exp2_fast(float x) { return __expf(x * LN2); }
#endif
#if __has_builtin(__builtin_amdgcn_logf)
static __device__ __forceinline__ float log2_fast(float x) { return __builtin_amdgcn_logf(x); }
#else
static __device__ __forceinline__ float log2_fast(float x) { return __logf(x) * LOG2E; }
#endif

#if __has_builtin(__builtin_amdgcn_cvt_pk_fp8_f32)
static __device__ __forceinline__ unsigned int pack4_fp8(float a, float b, float c, float d) {
    int v = 0;
    v = __builtin_amdgcn_cvt_pk_fp8_f32(a, b, v, false);
    v = __builtin_amdgcn_cvt_pk_fp8_f32(c, d, v, true);
    return (unsigned int)v;
}
#else
#include <hip/hip_fp8.h>
static __device__ __forceinline__ unsigned char cv1(float x) {
    __hip_fp8_e4m3 f(x);
    union { __hip_fp8_e4m3 f; unsigned char b; } u; u.f = f; return u.b;
}
static __device__ __forceinline__ unsigned int pack4_fp8(float a, float b, float c, float d) {
    return (unsigned int)cv1(a) | ((unsigned int)cv1(b) << 8) |
           ((unsigned int)cv1(c) << 16) | ((unsigned int)cv1(d) << 24);
}
#endif

// K=64 fp8 MFMA (32x32): MX-scaled if available, else 4x K=16 non-scaled.
static __device__ __forceinline__ f32x16 mfma_fp8_32x32_k64(i32x8 a, i32x8 b, f32x16 c) {
#if __has_builtin(__builtin_amdgcn_mfma_scale_f32_32x32x64_f8f6f4)
    return __builtin_amdgcn_mfma_scale_f32_32x32x64_f8f6f4(a, b, c, 0, 0, 0, 127, 0, 127);
#else
    union { i32x8 v; long l[4]; } ua, ub;
    ua.v = a; ub.v = b;
#pragma unroll
    for (int s = 0; s < 4; ++s)
        c = __builtin_amdgcn_mfma_f32_32x32x16_fp8_fp8(ua.l[s], ub.l[s], c, 0, 0, 0);
    return c;
#endif
}

// Counted waitcnt: loads complete oldest-first for vmcnt purposes (m135),
// so vmcnt(N) guarantees the (outstanding-N) oldest are done. Per-wave wait
// + s_barrier => collective completion (pattern proven in R6/R7).
#define VMWAIT(n) asm volatile("s_waitcnt vmcnt(" #n ")" ::: "memory")

// Kernel 1 (ILP-4, best measured): L2-normalize fp32 -> fp8 e4m3, k-major
// strips: byte(row,k) -> strip(row>>7)*32768 + (k>>4)*2048 + (row&127)*16
// + (k&15). Four rows per wave; independent loads/reductions pipelined.
// LESSONS KEPT: no cooperative launch (R4: silent no-op); no per-block
// device-scope fence/atomic of ANY kind (R1/R8: L2 poison, 390/557 us);
// R9's LDS-transpose store variant was NOT faster — scatter stores are fine.
__global__ __launch_bounds__(256) void norm_cast_kernel(
    const float* __restrict__ img, const float* __restrict__ txt,
    unsigned char* __restrict__ Ab, unsigned char* __restrict__ Bb, int N)
{
    const int wave = threadIdx.x >> 6;
    const int lane = threadIdx.x & 63;
    const int base = blockIdx.x * 16 + wave * 4;   // 4 rows per wave

    float4 v[4];
#pragma unroll
    for (int i = 0; i < 4; ++i) {
        int gRow = base + i;
        int row  = (gRow < N) ? gRow : gRow - N;
        const float* src = ((gRow < N) ? img : txt) + (size_t)row * D_DIM;
        v[i] = ((const float4*)src)[lane];
    }

    float ss[4];
#pragma unroll
    for (int i = 0; i < 4; ++i)
        ss[i] = v[i].x*v[i].x + v[i].y*v[i].y + v[i].z*v[i].z + v[i].w*v[i].w;

#pragma unroll
    for (int off = 1; off < 64; off <<= 1) {
#pragma unroll
        for (int i = 0; i < 4; ++i)
            ss[i] += __shfl_xor(ss[i], off, 64);
    }

#pragma unroll
    for (int i = 0; i < 4; ++i) {
        int gRow = base + i;
        int row  = (gRow < N) ? gRow : gRow - N;
        unsigned char* dstB = (gRow < N) ? Ab : Bb;
        float inv = 1.0f / fmaxf(sqrtf(ss[i]), 1e-12f);   // F.normalize eps
        unsigned int w = pack4_fp8(v[i].x*inv, v[i].y*inv, v[i].z*inv, v[i].w*inv);
        unsigned char* dst = dstB + (size_t)(row >> 7) * STRIP_BYTES
                           + (lane >> 2) * 2048 + (row & 127) * 16 + (lane & 3) * 4;
        *(unsigned int*)dst = w;
    }
}

// Kernel 2 (R10): fp8-MX Gram + softplus-sum + inline diag.
// R7's counted-vmcnt 2-buffer ring, extended to CHAIN 4 ROW-ADJACENT TILES
// per block (grid 4096, same bx -> B-strip reused 4x). The ring runs
// continuously over 16 chunks: tile t+1's chunks stage under tile t's last
// bodies, and each inter-tile epilogue (~550 cy pure VALU, no LDS) covers
// the just-issued stage's L2 latency. Removes 3 pipeline fills + 3
// uncovered epilogues per block (~15% of tile time). R7 counters showed
// VALU+MFMA issue = 88% -> the win must be removing dead boundary cycles,
// not more scheduling polish.
// Per-block partial is STORED (plain). NEVER a same-address RMW and NEVER a
// per-block device-scope fence/release (R1/R8: L2 poison, 390/557 us).
__global__ __launch_bounds__(256, 4) void siglip_loss_kernel(
    const unsigned char* __restrict__ A, const unsigned char* __restrict__ B,
    const float* __restrict__ t_prime, const float* __restrict__ bias,
    float* __restrict__ partials, int N)
{
    __shared__ unsigned char As[2][8192];   // [kc16 0..3][row 0..127][16B]
    __shared__ unsigned char Bs[2][8192];
    __shared__ float red[4];

    const int tid  = threadIdx.x;
    const int wave = tid >> 6;
    const int lane = tid & 63;
    const int r31  = lane & 31;
    const int g    = lane >> 5;       // k-group (2 kc16 chunks of the 4)
    const int wv   = wave >> 1;       // 0..1 row half
    const int wu   = wave & 1;        // 0..1 col half

    // Supertile swizzle, grid 4096: bid -> (bx in [0,128), byg in [0,32)).
    // Block handles tiles (by = byg*4 + t, bx), t = 0..3 — same B-strip.
    const int bid = blockIdx.x;
    const int st  = bid >> 8;         // 0..15
    const int l2  = bid & 255;
    const int bx  = (st & 7) * 16 + (l2 & 15);
    const int byg = (st >> 3) * 16 + (l2 >> 4);

    const unsigned char* Bstrip = B + (size_t)bx * STRIP_BYTES;
    const unsigned char* Abase  = A + (size_t)(byg * 4) * STRIP_BYTES;

    // Stage chunk c of tile t into buffer buf: 16 KB = 32 x 1KB wave-loads,
    // exactly 4 global_load_lds per wave (the vmcnt bookkeeping unit).
    auto stage = [&](int buf, int t, int c) {
        const unsigned char* ga = Abase + (size_t)t * STRIP_BYTES + c * 8192;
        const unsigned char* gb = Bstrip + c * 8192;
#pragma unroll
        for (int l = 0; l < 2; ++l) {
            int idx = wave * 2 + l;   // 0..7
            __builtin_amdgcn_global_load_lds(
                (const __attribute__((address_space(1))) unsigned int*)(ga + idx * 1024 + lane * 16),
                (__attribute__((address_space(3))) unsigned int*)&As[buf][idx * 1024],
                16, 0, 0);
            __builtin_amdgcn_global_load_lds(
                (const __attribute__((address_space(1))) unsigned int*)(gb + idx * 1024 + lane * 16),
                (__attribute__((address_space(3))) unsigned int*)&Bs[buf][idx * 1024],
                16, 0, 0);
        }
    };

    // Fragment LDS offsets (buffer-relative): kc_local = 2g (+1 at +2048).
    int a_off[2], b_off[2];
#pragma unroll
    for (int i = 0; i < 2; ++i) a_off[i] = g * 4096 + (wv * 64 + i * 32 + r31) * 16;
#pragma unroll
    for (int j = 0; j < 2; ++j) b_off[j] = g * 4096 + (wu * 64 + j * 32 + r31) * 16;

    f32x16 acc[2][2] = {};
    float local = 0.0f;
    const float s2 = __expf(t_prime[0]) * LOG2E;
    const float b2 = bias[0] * LOG2E;
    union F { i32x8 v8; i32x4 v4[2]; };

    auto body = [&](const unsigned char* as, const unsigned char* bs) {
        F a[2], b[2];
#pragma unroll
        for (int i = 0; i < 2; ++i) {
            a[i].v4[0] = *(const i32x4*)&as[a_off[i]];
            a[i].v4[1] = *(const i32x4*)&as[a_off[i] + 2048];
            b[i].v4[0] = *(const i32x4*)&bs[b_off[i]];
            b[i].v4[1] = *(const i32x4*)&bs[b_off[i] + 2048];
        }
#pragma unroll
        for (int i = 0; i < 2; ++i)
#pragma unroll
            for (int j = 0; j < 2; ++j)
                acc[i][j] = mfma_fp8_32x32_k64(a[i].v8, b[j].v8, acc[i][j]);
    };

    // Per-tile epilogue: softplus-sum tile t's acc into `local`, diag fix,
    // reset acc. Pure VALU / registers — no LDS, safe to overlap staging.
    auto epilogue = [&](int t) {
#pragma unroll
        for (int i = 0; i < 2; ++i)
#pragma unroll
            for (int j = 0; j < 2; ++j)
#pragma unroll
                for (int g2 = 0; g2 < 2; ++g2) {
                    float x[8];
#pragma unroll
                    for (int e = 0; e < 8; ++e)
                        x[e] = exp2_fast(fmaf(s2, acc[i][j][g2 * 8 + e], b2));
                    float p = 1.0f + x[0];
#pragma unroll
                    for (int e = 1; e < 8; ++e)
                        p = fmaf(p, x[e], p);      // p *= (1 + x[e])
                    local += log2_fast(p);
                }
        // Diagonal tiles: softplus(-z) = softplus(z) - z -> subtract z2.
        if (byg * 4 + t == bx) {
#pragma unroll
            for (int i = 0; i < 2; ++i)
#pragma unroll
                for (int j = 0; j < 2; ++j)
#pragma unroll
                    for (int r = 0; r < 16; ++r) {
                        // 32x32 C/D layout (m74/m101): col = lane&31,
                        // row = (r&3) + 8*(r>>2) + 4*(lane>>5)
                        int rowf = (r & 3) + 8 * (r >> 2) + 4 * g;
                        int grow = wv * 64 + i * 32 + rowf;
                        int gcol = wu * 64 + j * 32 + r31;
                        if (grow == gcol) local -= fmaf(s2, acc[i][j][r], b2);
                    }
        }
#pragma unroll
        for (int i = 0; i < 2; ++i)
#pragma unroll
            for (int j = 0; j < 2; ++j)
#pragma unroll
                for (int e = 0; e < 16; ++e)
                    acc[i][j][e] = 0.0f;
    };

    // ---- continuous 16-chunk ring over 4 tiles (chunk k: tile k>>2, c k&3;
    //      buffer k&1). Invariants per iteration k:
    //      body(k-1) -> bar -> stage(k+1 into buf (k+1)&1 = buf of body k-1,
    //      WAR-safe) -> [epilogue if tile boundary] -> VMWAIT(4): chunk k's
    //      loads done (only k+1's 4 may pend) -> bar -> body(k).
    stage(0, 0, 0);
    stage(1, 0, 1);

    VMWAIT(4);
    __builtin_amdgcn_s_barrier();
    body(As[0], Bs[0]);                          // k = 0

#pragma unroll 1
    for (int k = 1; k < 15; ++k) {
        const int nk = k + 1;
        __builtin_amdgcn_s_barrier();            // all waves done reading buf nk&1
        stage(nk & 1, nk >> 2, nk & 3);
        if ((k & 3) == 0) epilogue((k >> 2) - 1);   // covers stage latency
        VMWAIT(4);
        __builtin_amdgcn_s_barrier();
        if (k & 1) body(As[1], Bs[1]); else body(As[0], Bs[0]);
    }

    VMWAIT(0);                                   // k = 15 drain
    __builtin_amdgcn_s_barrier();
    body(As[1], Bs[1]);
    epilogue(3);

    // Block reduction + plain partial store (contention-free).
#pragma unroll
    for (int off = 32; off > 0; off >>= 1)
        local += __shfl_xor(local, off, 64);
    if (lane == 0) red[wave] = local;
    __syncthreads();
    if (tid == 0)
        partials[bid] = (red[0] + red[1]) + (red[2] + red[3]);   // plain store
}

// Kernel 3: reduce 4096 per-block partials -> out[0]. One block, ~2 us.
__global__ __launch_bounds__(1024) void reduce_kernel(
    const float* __restrict__ partials, float* __restrict__ out, int N)
{
    __shared__ float red[16];
    const int tid  = threadIdx.x;
    const int wave = tid >> 6;
    const int lane = tid & 63;
    float s = 0.0f;
#pragma unroll 4
    for (int i = tid; i < GRID2; i += 1024)
        s += partials[i];
#pragma unroll
    for (int off = 32; off > 0; off >>= 1)
        s += __shfl_xor(s, off, 64);
    if (lane == 0) red[wave] = s;
    __syncthreads();
    if (tid == 0) {
        float t = 0.0f;
#pragma unroll
        for (int w = 0; w < 16; ++w) t += red[w];
        out[0] = t * (LN2 / (float)N);
    }
}

extern "C" void kernel_launch(void* const* d_in, const int* in_sizes, int n_in,
                              void* d_out, int out_size, void* d_ws, size_t ws_size,
                              hipStream_t stream) {
    const float* img = (const float*)d_in[0];
    const float* txt = (const float*)d_in[1];
    const float* tp  = (const float*)d_in[2];
    const float* bs  = (const float*)d_in[3];
    float* out = (float*)d_out;
    int N = in_sizes[0] / D_DIM;    // 16384

    unsigned char* Ab = (unsigned char*)d_ws;       // 4 MB (k-major strips)
    unsigned char* Bb = Ab + (size_t)N * D_DIM;     // +4 MB
    float* partials   = (float*)(Bb + (size_t)N * D_DIM);   // 16 KB

    norm_cast_kernel<<<(2 * N) / 16, 256, 0, stream>>>(img, txt, Ab, Bb, N);
    siglip_loss_kernel<<<GRID2, 256, 0, stream>>>(Ab, Bb, tp, bs, partials, N);
    reduce_kernel<<<1, 1024, 0, stream>>>(partials, out, N);
}

// Round 11
// 161.513 us; speedup vs baseline: 4.6041x; 4.6041x over previous
//
#include <hip/hip_runtime.h>

typedef int   i32x4 __attribute__((ext_vector_type(4)));
typedef int   i32x8 __attribute__((ext_vector_type(8)));
typedef float f32x16 __attribute__((ext_vector_type(16)));

#define D_DIM 256
#define LOG2E 1.4426950408889634f
#define LN2   0.6931471805599453f
// Transposed workspace layout: [strip of 128 rows][kc16 0..15][row 0..127][16B]
#define STRIP_BYTES 32768
#define NBLK 16384

#if __has_builtin(__builtin_amdgcn_exp2f)
static __device__ __forceinline__ float exp2_fast(float x) { return __builtin_amdgcn_exp2f(x); }
#else
static __device__ __forceinline__ float exp2_fast(float x) { return __expf(x * LN2); }
#endif
#if __has_builtin(__builtin_amdgcn_logf)
static __device__ __forceinline__ float log2_fast(float x) { return __builtin_amdgcn_logf(x); }
#else
static __device__ __forceinline__ float log2_fast(float x) { return __logf(x) * LOG2E; }
#endif

#if __has_builtin(__builtin_amdgcn_cvt_pk_fp8_f32)
static __device__ __forceinline__ unsigned int pack4_fp8(float a, float b, float c, float d) {
    int v = 0;
    v = __builtin_amdgcn_cvt_pk_fp8_f32(a, b, v, false);
    v = __builtin_amdgcn_cvt_pk_fp8_f32(c, d, v, true);
    return (unsigned int)v;
}
#else
#include <hip/hip_fp8.h>
static __device__ __forceinline__ unsigned char cv1(float x) {
    __hip_fp8_e4m3 f(x);
    union { __hip_fp8_e4m3 f; unsigned char b; } u; u.f = f; return u.b;
}
static __device__ __forceinline__ unsigned int pack4_fp8(float a, float b, float c, float d) {
    return (unsigned int)cv1(a) | ((unsigned int)cv1(b) << 8) |
           ((unsigned int)cv1(c) << 16) | ((unsigned int)cv1(d) << 24);
}
#endif

// K=64 fp8 MFMA (32x32): MX-scaled if available, else 4x K=16 non-scaled.
static __device__ __forceinline__ f32x16 mfma_fp8_32x32_k64(i32x8 a, i32x8 b, f32x16 c) {
#if __has_builtin(__builtin_amdgcn_mfma_scale_f32_32x32x64_f8f6f4)
    return __builtin_amdgcn_mfma_scale_f32_32x32x64_f8f6f4(a, b, c, 0, 0, 0, 127, 0, 127);
#else
    union { i32x8 v; long l[4]; } ua, ub;
    ua.v = a; ub.v = b;
#pragma unroll
    for (int s = 0; s < 4; ++s)
        c = __builtin_amdgcn_mfma_f32_32x32x16_fp8_fp8(ua.l[s], ub.l[s], c, 0, 0, 0);
    return c;
#endif
}

// Counted waitcnt: loads complete oldest-first for vmcnt purposes (m135),
// so vmcnt(N) guarantees the (outstanding-N) oldest are done. Per-wave wait
// + s_barrier => collective completion (pattern proven in R6/R7).
#define VMWAIT(n) asm volatile("s_waitcnt vmcnt(" #n ")" ::: "memory")

// Kernel 1 (ILP-4, best measured): L2-normalize fp32 -> fp8 e4m3, k-major
// strips: byte(row,k) -> strip(row>>7)*32768 + (k>>4)*2048 + (row&127)*16
// + (k&15). Four rows per wave; independent loads/reductions pipelined.
// LESSONS KEPT: no cooperative launch (R4: silent no-op); no per-block
// device-scope fence/atomic of ANY kind (R1/R8: L2 poison, 390/557 us);
// LDS-transpose stores (R9) and 1-row/wave (R2) were not faster.
__global__ __launch_bounds__(256) void norm_cast_kernel(
    const float* __restrict__ img, const float* __restrict__ txt,
    unsigned char* __restrict__ Ab, unsigned char* __restrict__ Bb, int N)
{
    const int wave = threadIdx.x >> 6;
    const int lane = threadIdx.x & 63;
    const int base = blockIdx.x * 16 + wave * 4;   // 4 rows per wave

    float4 v[4];
#pragma unroll
    for (int i = 0; i < 4; ++i) {
        int gRow = base + i;
        int row  = (gRow < N) ? gRow : gRow - N;
        const float* src = ((gRow < N) ? img : txt) + (size_t)row * D_DIM;
        v[i] = ((const float4*)src)[lane];
    }

    float ss[4];
#pragma unroll
    for (int i = 0; i < 4; ++i)
        ss[i] = v[i].x*v[i].x + v[i].y*v[i].y + v[i].z*v[i].z + v[i].w*v[i].w;

#pragma unroll
    for (int off = 1; off < 64; off <<= 1) {
#pragma unroll
        for (int i = 0; i < 4; ++i)
            ss[i] += __shfl_xor(ss[i], off, 64);
    }

#pragma unroll
    for (int i = 0; i < 4; ++i) {
        int gRow = base + i;
        int row  = (gRow < N) ? gRow : gRow - N;
        unsigned char* dstB = (gRow < N) ? Ab : Bb;
        float inv = 1.0f / fmaxf(sqrtf(ss[i]), 1e-12f);   // F.normalize eps
        unsigned int w = pack4_fp8(v[i].x*inv, v[i].y*inv, v[i].z*inv, v[i].w*inv);
        unsigned char* dst = dstB + (size_t)(row >> 7) * STRIP_BYTES
                           + (lane >> 2) * 2048 + (row & 127) * 16 + (lane & 3) * 4;
        *(unsigned int*)dst = w;
    }
}

// Kernel 2 (R7, verified 88 us): fp8-MX Gram + softplus-sum + inline diag,
// counted-vmcnt 2-buffer ring (depth-1 prefetch, 32.8 KB LDS -> 4 blocks/CU):
//   stage c0,c1 | w(4) bar body(b0) | bar stage c2 w(4) bar body(b1)
//   | bar stage c3 w(4) bar body(b0) | w(0) bar body(b1)
// STRUCTURE IS STRAIGHT-LINE ON PURPOSE: the epilogue runs ONCE, at the end,
// after staging registers die — acc stays in AGPRs for the whole ring. R10
// put the epilogue inside a runtime loop (tile chaining) and the allocator
// spilled acc to scratch under the 128-VGPR launch-bounds cap: WRITE_SIZE
// 512 KB -> 2.6 GB, 88 -> 700 us. Do not re-introduce mid-loop epilogues.
// Per-block partial is STORED (plain). NEVER a same-address RMW and NEVER a
// per-block device-scope fence/release (R1/R8: L2 poison, 390/557 us).
__global__ __launch_bounds__(256, 4) void siglip_loss_kernel(
    const unsigned char* __restrict__ A, const unsigned char* __restrict__ B,
    const float* __restrict__ t_prime, const float* __restrict__ bias,
    float* __restrict__ partials, int N)
{
    __shared__ unsigned char As[2][8192];   // [kc16 0..3][row 0..127][16B]
    __shared__ unsigned char Bs[2][8192];
    __shared__ float red[4];

    const int tid  = threadIdx.x;
    const int wave = tid >> 6;
    const int lane = tid & 63;
    const int r31  = lane & 31;
    const int g    = lane >> 5;       // k-group (2 kc16 chunks of the 4)
    const int wv   = wave >> 1;       // 0..1 row half
    const int wu   = wave & 1;        // 0..1 col half

    // 16x16 supertile swizzle for L2 locality (grid 16384 flat).
    const int bid = blockIdx.x;
    const int st  = bid >> 8;
    const int l2  = bid & 255;
    const int bx  = (st & 7) * 16 + (l2 & 15);
    const int by  = (st >> 3) * 16 + (l2 >> 4);
    const int rowBase = by * 128;
    const int colBase = bx * 128;

    const unsigned char* Astrip = A + (size_t)by * STRIP_BYTES;
    const unsigned char* Bstrip = B + (size_t)bx * STRIP_BYTES;

    // Stage K-chunk c into buffer buf: 16 KB = 32 x 1KB wave-loads,
    // exactly 4 global_load_lds per wave (the vmcnt bookkeeping unit).
    auto stage = [&](int buf, int c) {
        const unsigned char* ga = Astrip + c * 8192;
        const unsigned char* gb = Bstrip + c * 8192;
#pragma unroll
        for (int l = 0; l < 2; ++l) {
            int idx = wave * 2 + l;   // 0..7
            __builtin_amdgcn_global_load_lds(
                (const __attribute__((address_space(1))) unsigned int*)(ga + idx * 1024 + lane * 16),
                (__attribute__((address_space(3))) unsigned int*)&As[buf][idx * 1024],
                16, 0, 0);
            __builtin_amdgcn_global_load_lds(
                (const __attribute__((address_space(1))) unsigned int*)(gb + idx * 1024 + lane * 16),
                (__attribute__((address_space(3))) unsigned int*)&Bs[buf][idx * 1024],
                16, 0, 0);
        }
    };

    // Fragment LDS offsets (buffer-relative): kc_local = 2g (+1 at +2048).
    int a_off[2], b_off[2];
#pragma unroll
    for (int i = 0; i < 2; ++i) a_off[i] = g * 4096 + (wv * 64 + i * 32 + r31) * 16;
#pragma unroll
    for (int j = 0; j < 2; ++j) b_off[j] = g * 4096 + (wu * 64 + j * 32 + r31) * 16;

    f32x16 acc[2][2] = {};
    union F { i32x8 v8; i32x4 v4[2]; };

    auto body = [&](const unsigned char* as, const unsigned char* bs) {
        F a[2], b[2];
#pragma unroll
        for (int i = 0; i < 2; ++i) {
            a[i].v4[0] = *(const i32x4*)&as[a_off[i]];
            a[i].v4[1] = *(const i32x4*)&as[a_off[i] + 2048];
            b[i].v4[0] = *(const i32x4*)&bs[b_off[i]];
            b[i].v4[1] = *(const i32x4*)&bs[b_off[i] + 2048];
        }
#pragma unroll
        for (int i = 0; i < 2; ++i)
#pragma unroll
            for (int j = 0; j < 2; ++j)
                acc[i][j] = mfma_fp8_32x32_k64(a[i].v8, b[j].v8, acc[i][j]);
    };

    // ---- counted-vmcnt 2-buffer ring (depth-1 prefetch, 4 blocks/CU) ----
    stage(0, 0);                       // 4 outstanding
    stage(1, 1);                       // 8 outstanding

    VMWAIT(4);                         // own c0 loads done (c1 in flight)
    __builtin_amdgcn_s_barrier();      // everyone's c0 done
    body(As[0], Bs[0]);

    __builtin_amdgcn_s_barrier();      // all waves done READING buf0
    stage(0, 2);                       // c2 -> buf0; <=8 outstanding
    VMWAIT(4);                         // own c1 done (c2 in flight)
    __builtin_amdgcn_s_barrier();      // everyone's c1 done
    body(As[1], Bs[1]);

    __builtin_amdgcn_s_barrier();      // all waves done reading buf1
    stage(1, 3);                       // c3 -> buf1; <=8 outstanding
    VMWAIT(4);                         // own c2 done (c3 in flight)
    __builtin_amdgcn_s_barrier();      // everyone's c2 done
    body(As[0], Bs[0]);

    VMWAIT(0);                         // own c3 done (buf0 not rewritten)
    __builtin_amdgcn_s_barrier();      // everyone's c3 done
    body(As[1], Bs[1]);

    // Epilogue: z2 = s2*acc + b2 (log2 domain); log2 of products of 8.
    const float s2 = __expf(t_prime[0]) * LOG2E;
    const float b2 = bias[0] * LOG2E;
    float local = 0.0f;
#pragma unroll
    for (int i = 0; i < 2; ++i)
#pragma unroll
        for (int j = 0; j < 2; ++j)
#pragma unroll
            for (int g2 = 0; g2 < 2; ++g2) {
                float x[8];
#pragma unroll
                for (int e = 0; e < 8; ++e)
                    x[e] = exp2_fast(fmaf(s2, acc[i][j][g2 * 8 + e], b2));
                float p = 1.0f + x[0];
#pragma unroll
                for (int e = 1; e < 8; ++e)
                    p = fmaf(p, x[e], p);      // p *= (1 + x[e])
                local += log2_fast(p);
            }

    // Diagonal blocks: softplus(-z) = softplus(z) - z -> subtract z2.
    if (rowBase == colBase) {
#pragma unroll
        for (int i = 0; i < 2; ++i)
#pragma unroll
            for (int j = 0; j < 2; ++j)
#pragma unroll
                for (int r = 0; r < 16; ++r) {
                    // 32x32 C/D layout (m74/m101): col = lane&31,
                    // row = (r&3) + 8*(r>>2) + 4*(lane>>5)
                    int rowf = (r & 3) + 8 * (r >> 2) + 4 * g;
                    int grow = wv * 64 + i * 32 + rowf;
                    int gcol = wu * 64 + j * 32 + r31;
                    if (grow == gcol) local -= fmaf(s2, acc[i][j][r], b2);
                }
    }

#pragma unroll
    for (int off = 32; off > 0; off >>= 1)
        local += __shfl_xor(local, off, 64);
    if (lane == 0) red[wave] = local;
    __syncthreads();
    if (tid == 0)
        partials[bid] = (red[0] + red[1]) + (red[2] + red[3]);   // plain store
}

// Kernel 3: reduce 16384 per-block partials -> out[0]. One block, ~3 us.
__global__ __launch_bounds__(1024) void reduce_kernel(
    const float* __restrict__ partials, float* __restrict__ out, int N)
{
    __shared__ float red[16];
    const int tid  = threadIdx.x;
    const int wave = tid >> 6;
    const int lane = tid & 63;
    float s = 0.0f;
#pragma unroll 4
    for (int i = tid; i < NBLK; i += 1024)
        s += partials[i];
#pragma unroll
    for (int off = 32; off > 0; off >>= 1)
        s += __shfl_xor(s, off, 64);
    if (lane == 0) red[wave] = s;
    __syncthreads();
    if (tid == 0) {
        float t = 0.0f;
#pragma unroll
        for (int w = 0; w < 16; ++w) t += red[w];
        out[0] = t * (LN2 / (float)N);
    }
}

extern "C" void kernel_launch(void* const* d_in, const int* in_sizes, int n_in,
                              void* d_out, int out_size, void* d_ws, size_t ws_size,
                              hipStream_t stream) {
    const float* img = (const float*)d_in[0];
    const float* txt = (const float*)d_in[1];
    const float* tp  = (const float*)d_in[2];
    const float* bs  = (const float*)d_in[3];
    float* out = (float*)d_out;
    int N = in_sizes[0] / D_DIM;    // 16384

    unsigned char* Ab = (unsigned char*)d_ws;       // 4 MB (k-major strips)
    unsigned char* Bb = Ab + (size_t)N * D_DIM;     // +4 MB
    float* partials   = (float*)(Bb + (size_t)N * D_DIM);   // 64 KB

    norm_cast_kernel<<<(2 * N) / 16, 256, 0, stream>>>(img, txt, Ab, Bb, N);
    siglip_loss_kernel<<<NBLK, 256, 0, stream>>>(Ab, Bb, tp, bs, partials, N);
    reduce_kernel<<<1, 1024, 0, stream>>>(partials, out, N);
}

// Round 12
// 156.200 us; speedup vs baseline: 4.7607x; 1.0340x over previous
//
#include <hip/hip_runtime.h>

typedef int   i32x4 __attribute__((ext_vector_type(4)));
typedef int   i32x8 __attribute__((ext_vector_type(8)));
typedef float f32x16 __attribute__((ext_vector_type(16)));

#define D_DIM 256
#define LOG2E 1.4426950408889634f
#define LN2   0.6931471805599453f
// Transposed workspace layout: [strip of 128 rows][kc16 0..15][row 0..127][16B]
#define STRIP_BYTES 32768
#define GRID2 8192          // siglip: each block chains 2 row-adjacent tiles

#if __has_builtin(__builtin_amdgcn_exp2f)
static __device__ __forceinline__ float exp2_fast(float x) { return __builtin_amdgcn_exp2f(x); }
#else
static __device__ __forceinline__ float exp2_fast(float x) { return __expf(x * LN2); }
#endif
#if __has_builtin(__builtin_amdgcn_logf)
static __device__ __forceinline__ float log2_fast(float x) { return __builtin_amdgcn_logf(x); }
#else
static __device__ __forceinline__ float log2_fast(float x) { return __logf(x) * LOG2E; }
#endif

#if __has_builtin(__builtin_amdgcn_cvt_pk_fp8_f32)
static __device__ __forceinline__ unsigned int pack4_fp8(float a, float b, float c, float d) {
    int v = 0;
    v = __builtin_amdgcn_cvt_pk_fp8_f32(a, b, v, false);
    v = __builtin_amdgcn_cvt_pk_fp8_f32(c, d, v, true);
    return (unsigned int)v;
}
#else
#include <hip/hip_fp8.h>
static __device__ __forceinline__ unsigned char cv1(float x) {
    __hip_fp8_e4m3 f(x);
    union { __hip_fp8_e4m3 f; unsigned char b; } u; u.f = f; return u.b;
}
static __device__ __forceinline__ unsigned int pack4_fp8(float a, float b, float c, float d) {
    return (unsigned int)cv1(a) | ((unsigned int)cv1(b) << 8) |
           ((unsigned int)cv1(c) << 16) | ((unsigned int)cv1(d) << 24);
}
#endif

// K=64 fp8 MFMA (32x32): MX-scaled if available, else 4x K=16 non-scaled.
static __device__ __forceinline__ f32x16 mfma_fp8_32x32_k64(i32x8 a, i32x8 b, f32x16 c) {
#if __has_builtin(__builtin_amdgcn_mfma_scale_f32_32x32x64_f8f6f4)
    return __builtin_amdgcn_mfma_scale_f32_32x32x64_f8f6f4(a, b, c, 0, 0, 0, 127, 0, 127);
#else
    union { i32x8 v; long l[4]; } ua, ub;
    ua.v = a; ub.v = b;
#pragma unroll
    for (int s = 0; s < 4; ++s)
        c = __builtin_amdgcn_mfma_f32_32x32x16_fp8_fp8(ua.l[s], ub.l[s], c, 0, 0, 0);
    return c;
#endif
}

// Counted waitcnt: loads complete oldest-first for vmcnt purposes (m135),
// so vmcnt(N) guarantees the (outstanding-N) oldest are done. Per-wave wait
// + s_barrier => collective completion (pattern proven in R6/R7/R11).
#define VMWAIT(n) asm volatile("s_waitcnt vmcnt(" #n ")" ::: "memory")

// Kernel 1 (ILP-4, best measured): L2-normalize fp32 -> fp8 e4m3, k-major
// strips: byte(row,k) -> strip(row>>7)*32768 + (k>>4)*2048 + (row&127)*16
// + (k&15). Four rows per wave; independent loads/reductions pipelined.
// LESSONS KEPT: no cooperative launch (R4: silent no-op); no per-block
// device-scope fence/atomic of ANY kind (R1/R8: L2 poison, 390/557 us);
// LDS-transpose stores (R9) and 1-row/wave (R2) were not faster.
__global__ __launch_bounds__(256) void norm_cast_kernel(
    const float* __restrict__ img, const float* __restrict__ txt,
    unsigned char* __restrict__ Ab, unsigned char* __restrict__ Bb, int N)
{
    const int wave = threadIdx.x >> 6;
    const int lane = threadIdx.x & 63;
    const int base = blockIdx.x * 16 + wave * 4;   // 4 rows per wave

    float4 v[4];
#pragma unroll
    for (int i = 0; i < 4; ++i) {
        int gRow = base + i;
        int row  = (gRow < N) ? gRow : gRow - N;
        const float* src = ((gRow < N) ? img : txt) + (size_t)row * D_DIM;
        v[i] = ((const float4*)src)[lane];
    }

    float ss[4];
#pragma unroll
    for (int i = 0; i < 4; ++i)
        ss[i] = v[i].x*v[i].x + v[i].y*v[i].y + v[i].z*v[i].z + v[i].w*v[i].w;

#pragma unroll
    for (int off = 1; off < 64; off <<= 1) {
#pragma unroll
        for (int i = 0; i < 4; ++i)
            ss[i] += __shfl_xor(ss[i], off, 64);
    }

#pragma unroll
    for (int i = 0; i < 4; ++i) {
        int gRow = base + i;
        int row  = (gRow < N) ? gRow : gRow - N;
        unsigned char* dstB = (gRow < N) ? Ab : Bb;
        float inv = 1.0f / fmaxf(sqrtf(ss[i]), 1e-12f);   // F.normalize eps
        unsigned int w = pack4_fp8(v[i].x*inv, v[i].y*inv, v[i].z*inv, v[i].w*inv);
        unsigned char* dst = dstB + (size_t)(row >> 7) * STRIP_BYTES
                           + (lane >> 2) * 2048 + (row & 127) * 16 + (lane & 3) * 4;
        *(unsigned int*)dst = w;
    }
}

// Kernel 2 (R12): fp8-MX Gram + softplus-sum + inline diag.
// STRAIGHT-LINE 2-TILE CHAIN: two complete R7 counted-vmcnt rings
// concatenated (same bx -> B-strip L2-reused; adjacent by). Tile 1's first
// two chunks are issued BEFORE epilogue 0, so the second pipeline fill hides
// under the ~800-cy pure-VALU epilogue. Everything is straight-line:
// R10's scratch-spill came from a mid-RUNTIME-LOOP epilogue making acc
// VALU-addressable (WRITE_SIZE 512 KB -> 2.6 GB); here each epilogue is a
// one-time inline call with only two base pointers extra-live
// (global_load_lds has no VGPR destination).
// Schedule invariant per chunk (proven R6/R7/R11): readers-done barrier ->
// stage -> VMWAIT(4) (8 outstanding before, so prior chunk complete) ->
// data-ready barrier -> body. Never vmcnt(0) except the final chunk.
// Per-block partial is STORED (plain). NEVER a same-address RMW and NEVER a
// per-block device-scope fence/release (R1/R8: L2 poison, 390/557 us).
__global__ __launch_bounds__(256, 4) void siglip_loss_kernel(
    const unsigned char* __restrict__ A, const unsigned char* __restrict__ B,
    const float* __restrict__ t_prime, const float* __restrict__ bias,
    float* __restrict__ partials, int N)
{
    __shared__ unsigned char As[2][8192];   // [kc16 0..3][row 0..127][16B]
    __shared__ unsigned char Bs[2][8192];
    __shared__ float red[4];

    const int tid  = threadIdx.x;
    const int wave = tid >> 6;
    const int lane = tid & 63;
    const int r31  = lane & 31;
    const int g    = lane >> 5;       // k-group (2 kc16 chunks of the 4)
    const int wv   = wave >> 1;       // 0..1 row half
    const int wu   = wave & 1;        // 0..1 col half

    // Supertile swizzle, grid 8192: bid -> (bx in [0,128), byg in [0,64)).
    // Block handles tiles (by = byg*2 + t, bx), t = 0..1 — same B-strip.
    const int bid = blockIdx.x;
    const int st  = bid >> 8;         // 0..31
    const int l2  = bid & 255;
    const int bx  = (st & 7) * 16 + (l2 & 15);
    const int byg = (st >> 3) * 16 + (l2 >> 4);

    const unsigned char* Bstrip = B + (size_t)bx * STRIP_BYTES;
    const unsigned char* A0 = A + (size_t)(byg * 2 + 0) * STRIP_BYTES;
    const unsigned char* A1 = A + (size_t)(byg * 2 + 1) * STRIP_BYTES;

    // Stage chunk c (A from `astrip`, B from Bstrip) into buffer buf:
    // 16 KB = 32 x 1KB wave-loads, exactly 4 global_load_lds per wave.
    auto stage = [&](int buf, const unsigned char* astrip, int c) {
        const unsigned char* ga = astrip + c * 8192;
        const unsigned char* gb = Bstrip + c * 8192;
#pragma unroll
        for (int l = 0; l < 2; ++l) {
            int idx = wave * 2 + l;   // 0..7
            __builtin_amdgcn_global_load_lds(
                (const __attribute__((address_space(1))) unsigned int*)(ga + idx * 1024 + lane * 16),
                (__attribute__((address_space(3))) unsigned int*)&As[buf][idx * 1024],
                16, 0, 0);
            __builtin_amdgcn_global_load_lds(
                (const __attribute__((address_space(1))) unsigned int*)(gb + idx * 1024 + lane * 16),
                (__attribute__((address_space(3))) unsigned int*)&Bs[buf][idx * 1024],
                16, 0, 0);
        }
    };

    // Fragment LDS offsets (buffer-relative): kc_local = 2g (+1 at +2048).
    int a_off[2], b_off[2];
#pragma unroll
    for (int i = 0; i < 2; ++i) a_off[i] = g * 4096 + (wv * 64 + i * 32 + r31) * 16;
#pragma unroll
    for (int j = 0; j < 2; ++j) b_off[j] = g * 4096 + (wu * 64 + j * 32 + r31) * 16;

    f32x16 acc[2][2] = {};
    float local = 0.0f;
    const float s2 = __expf(t_prime[0]) * LOG2E;
    const float b2 = bias[0] * LOG2E;
    union F { i32x8 v8; i32x4 v4[2]; };

    auto body = [&](const unsigned char* as, const unsigned char* bs) {
        F a[2], b[2];
#pragma unroll
        for (int i = 0; i < 2; ++i) {
            a[i].v4[0] = *(const i32x4*)&as[a_off[i]];
            a[i].v4[1] = *(const i32x4*)&as[a_off[i] + 2048];
            b[i].v4[0] = *(const i32x4*)&bs[b_off[i]];
            b[i].v4[1] = *(const i32x4*)&bs[b_off[i] + 2048];
        }
#pragma unroll
        for (int i = 0; i < 2; ++i)
#pragma unroll
            for (int j = 0; j < 2; ++j)
                acc[i][j] = mfma_fp8_32x32_k64(a[i].v8, b[j].v8, acc[i][j]);
    };

    // Softplus-sum acc into `local` (+ diag fix for tile row tby), reset acc.
    // Pure VALU/registers — no LDS; called twice from straight-line code.
    auto epilogue = [&](int tby) {
#pragma unroll
        for (int i = 0; i < 2; ++i)
#pragma unroll
            for (int j = 0; j < 2; ++j)
#pragma unroll
                for (int g2 = 0; g2 < 2; ++g2) {
                    float x[8];
#pragma unroll
                    for (int e = 0; e < 8; ++e)
                        x[e] = exp2_fast(fmaf(s2, acc[i][j][g2 * 8 + e], b2));
                    float p = 1.0f + x[0];
#pragma unroll
                    for (int e = 1; e < 8; ++e)
                        p = fmaf(p, x[e], p);      // p *= (1 + x[e])
                    local += log2_fast(p);
                }
        if (tby == bx) {    // diagonal tile: softplus(-z) = softplus(z) - z
#pragma unroll
            for (int i = 0; i < 2; ++i)
#pragma unroll
                for (int j = 0; j < 2; ++j)
#pragma unroll
                    for (int r = 0; r < 16; ++r) {
                        // 32x32 C/D layout (m74/m101): col = lane&31,
                        // row = (r&3) + 8*(r>>2) + 4*(lane>>5)
                        int rowf = (r & 3) + 8 * (r >> 2) + 4 * g;
                        int grow = wv * 64 + i * 32 + rowf;
                        int gcol = wu * 64 + j * 32 + r31;
                        if (grow == gcol) local -= fmaf(s2, acc[i][j][r], b2);
                    }
        }
#pragma unroll
        for (int i = 0; i < 2; ++i)
#pragma unroll
            for (int j = 0; j < 2; ++j)
#pragma unroll
                for (int e = 0; e < 16; ++e)
                    acc[i][j][e] = 0.0f;
    };

    // ---- tile 0 ring (R7 schedule) ----
    stage(0, A0, 0);                   // 4 outstanding
    stage(1, A0, 1);                   // 8 outstanding

    VMWAIT(4);                         // t0c0 done (t0c1 in flight)
    __builtin_amdgcn_s_barrier();
    body(As[0], Bs[0]);                // t0c0

    __builtin_amdgcn_s_barrier();      // readers of buf0 done
    stage(0, A0, 2);
    VMWAIT(4);                         // t0c1 done (t0c2 in flight)
    __builtin_amdgcn_s_barrier();
    body(As[1], Bs[1]);                // t0c1

    __builtin_amdgcn_s_barrier();      // readers of buf1 done
    stage(1, A0, 3);
    VMWAIT(4);                         // t0c2 done (t0c3 in flight)
    __builtin_amdgcn_s_barrier();
    body(As[0], Bs[0]);                // t0c2

    __builtin_amdgcn_s_barrier();      // readers of buf0 done
    stage(0, A1, 0);                   // tile 1 prefetch begins
    VMWAIT(4);                         // t0c3 done (t1c0 in flight)
    __builtin_amdgcn_s_barrier();
    body(As[1], Bs[1]);                // t0c3

    // ---- tile boundary: issue t1c1, then epilogue 0 covers the fill ----
    __builtin_amdgcn_s_barrier();      // readers of buf1 done
    stage(1, A1, 1);                   // 8 outstanding (t1c0 + t1c1)
    epilogue(byg * 2 + 0);             // ~800 cy VALU hides t1 fill latency
    VMWAIT(4);                         // t1c0 done (t1c1 in flight)
    __builtin_amdgcn_s_barrier();
    body(As[0], Bs[0]);                // t1c0

    __builtin_amdgcn_s_barrier();      // readers of buf0 done
    stage(0, A1, 2);
    VMWAIT(4);                         // t1c1 done (t1c2 in flight)
    __builtin_amdgcn_s_barrier();
    body(As[1], Bs[1]);                // t1c1

    __builtin_amdgcn_s_barrier();      // readers of buf1 done
    stage(1, A1, 3);
    VMWAIT(4);                         // t1c2 done (t1c3 in flight)
    __builtin_amdgcn_s_barrier();
    body(As[0], Bs[0]);                // t1c2

    VMWAIT(0);                         // t1c3 done
    __builtin_amdgcn_s_barrier();
    body(As[1], Bs[1]);                // t1c3

    epilogue(byg * 2 + 1);

    // Block reduction + plain partial store (contention-free).
#pragma unroll
    for (int off = 32; off > 0; off >>= 1)
        local += __shfl_xor(local, off, 64);
    if (lane == 0) red[wave] = local;
    __syncthreads();
    if (tid == 0)
        partials[bid] = (red[0] + red[1]) + (red[2] + red[3]);   // plain store
}

// Kernel 3: reduce 8192 per-block partials -> out[0]. One block, ~3 us.
__global__ __launch_bounds__(1024) void reduce_kernel(
    const float* __restrict__ partials, float* __restrict__ out, int N)
{
    __shared__ float red[16];
    const int tid  = threadIdx.x;
    const int wave = tid >> 6;
    const int lane = tid & 63;
    float s = 0.0f;
#pragma unroll 4
    for (int i = tid; i < GRID2; i += 1024)
        s += partials[i];
#pragma unroll
    for (int off = 32; off > 0; off >>= 1)
        s += __shfl_xor(s, off, 64);
    if (lane == 0) red[wave] = s;
    __syncthreads();
    if (tid == 0) {
        float t = 0.0f;
#pragma unroll
        for (int w = 0; w < 16; ++w) t += red[w];
        out[0] = t * (LN2 / (float)N);
    }
}

extern "C" void kernel_launch(void* const* d_in, const int* in_sizes, int n_in,
                              void* d_out, int out_size, void* d_ws, size_t ws_size,
                              hipStream_t stream) {
    const float* img = (const float*)d_in[0];
    const float* txt = (const float*)d_in[1];
    const float* tp  = (const float*)d_in[2];
    const float* bs  = (const float*)d_in[3];
    float* out = (float*)d_out;
    int N = in_sizes[0] / D_DIM;    // 16384

    unsigned char* Ab = (unsigned char*)d_ws;       // 4 MB (k-major strips)
    unsigned char* Bb = Ab + (size_t)N * D_DIM;     // +4 MB
    float* partials   = (float*)(Bb + (size_t)N * D_DIM);   // 32 KB

    norm_cast_kernel<<<(2 * N) / 16, 256, 0, stream>>>(img, txt, Ab, Bb, N);
    siglip_loss_kernel<<<GRID2, 256, 0, stream>>>(Ab, Bb, tp, bs, partials, N);
    reduce_kernel<<<1, 1024, 0, stream>>>(partials, out, N);
}